// Round 1
// baseline (1176.160 us; speedup 1.0000x reference)
//
#include <hip/hip_runtime.h>

#define NBUCK 8192
#define IGNORE_LBL 255
#define PIX (4*384*384)

// ws layout:
//  0:  double ce_sum
//  8:  double dsn_sum
// 16:  double lov_sum[3]
// 40:  float  n_present[3]
// 52:  uint   valid_cnt
// 64:  u64    cntfg[12][NBUCK]   (count<<32 | fg_count)
// 64+12*NBUCK*8: float esum[12][NBUCK]

__device__ __forceinline__ void bilin_coords(int y, int x, int& y0, int& x0,
                                             float& w00, float& w01, float& w10, float& w11)
{
    const float scale = 95.0f / 383.0f;   // align_corners=True, 96 -> 384
    float sy = y * scale, sx = x * scale;
    y0 = (int)sy; if (y0 > 94) y0 = 94;
    x0 = (int)sx; if (x0 > 94) x0 = 94;
    float ty = sy - (float)y0, tx = sx - (float)x0;
    w00 = (1.0f - ty) * (1.0f - tx);
    w01 = (1.0f - ty) * tx;
    w10 = ty * (1.0f - tx);
    w11 = ty * tx;
}

// Branch 0: CE(pred) + CE(pred_dsn) + lovasz histograms for 7 classes
__global__ __launch_bounds__(256) void k_branch0(
    const float* __restrict__ p0, const float* __restrict__ pdsn,
    const int* __restrict__ lab,
    unsigned long long* __restrict__ cntfg, float* __restrict__ esum,
    double* __restrict__ ce_sum, double* __restrict__ dsn_sum,
    unsigned int* __restrict__ valid_cnt)
{
    int idx = blockIdx.x * 256 + threadIdx.x;
    float nll = 0.0f, nll2 = 0.0f;
    int v = 0;

    if (idx < PIX) {
        int x = idx % 384;
        int y = (idx / 384) % 384;
        int b = idx / (384 * 384);
        int y0, x0; float w00, w01, w10, w11;
        bilin_coords(y, x, y0, x0, w00, w01, w10, w11);
        int l = lab[idx];
        bool valid = (l != IGNORE_LBL);

        float z[7], z2[7];
        const int base_b = b * 7 * 96 * 96;
        const int off = y0 * 96 + x0;
        #pragma unroll
        for (int c = 0; c < 7; c++) {
            const float* q = p0 + base_b + c * 96 * 96 + off;
            z[c] = q[0] * w00 + q[1] * w01 + q[96] * w10 + q[97] * w11;
            const float* q2 = pdsn + base_b + c * 96 * 96 + off;
            z2[c] = q2[0] * w00 + q2[1] * w01 + q2[96] * w10 + q2[97] * w11;
        }

        // softmax / logsumexp for z
        float m = z[0];
        #pragma unroll
        for (int c = 1; c < 7; c++) m = fmaxf(m, z[c]);
        float p[7], s = 0.0f;
        #pragma unroll
        for (int c = 0; c < 7; c++) { p[c] = expf(z[c] - m); s += p[c]; }
        float inv = 1.0f / s;

        if (valid) {
            int lc = l; if (lc < 0) lc = 0; if (lc > 6) lc = 6;
            nll = logf(s) + m - z[lc];

            float m2 = z2[0];
            #pragma unroll
            for (int c = 1; c < 7; c++) m2 = fmaxf(m2, z2[c]);
            float s2 = 0.0f;
            #pragma unroll
            for (int c = 0; c < 7; c++) s2 += expf(z2[c] - m2);
            nll2 = logf(s2) + m2 - z2[lc];
            v = 1;

            #pragma unroll
            for (int c = 0; c < 7; c++) {
                float pc = p[c] * inv;
                int fg = (l == c) ? 1 : 0;
                float err = fabsf((float)fg - pc);
                int bk = (int)(err * (float)NBUCK);
                if (bk > NBUCK - 1) bk = NBUCK - 1;
                if (bk < 0) bk = 0;
                atomicAdd(&cntfg[(size_t)c * NBUCK + bk],
                          0x100000000ull | (unsigned long long)fg);
                atomicAdd(&esum[(size_t)c * NBUCK + bk], err);
            }
        }
    }

    // block reduce nll, nll2, v
    __shared__ float r1[256], r2[256];
    __shared__ int r3[256];
    int t = threadIdx.x;
    r1[t] = nll; r2[t] = nll2; r3[t] = v;
    __syncthreads();
    for (int o = 128; o > 0; o >>= 1) {
        if (t < o) { r1[t] += r1[t + o]; r2[t] += r2[t + o]; r3[t] += r3[t + o]; }
        __syncthreads();
    }
    if (t == 0) {
        atomicAdd(ce_sum, (double)r1[0]);
        atomicAdd(dsn_sum, (double)r2[0]);
        atomicAdd(valid_cnt, (unsigned int)r3[0]);
    }
}

// Lovasz histograms for a C-class branch (no CE)
template<int C>
__global__ __launch_bounds__(256) void k_lov(
    const float* __restrict__ pr, const int* __restrict__ lab,
    unsigned long long* __restrict__ cntfg, float* __restrict__ esum)
{
    int idx = blockIdx.x * 256 + threadIdx.x;
    if (idx >= PIX) return;
    int x = idx % 384;
    int y = (idx / 384) % 384;
    int b = idx / (384 * 384);
    int y0, x0; float w00, w01, w10, w11;
    bilin_coords(y, x, y0, x0, w00, w01, w10, w11);
    int l = lab[idx];
    if (l == IGNORE_LBL) return;

    float z[C];
    const int base_b = b * C * 96 * 96;
    const int off = y0 * 96 + x0;
    #pragma unroll
    for (int c = 0; c < C; c++) {
        const float* q = pr + base_b + c * 96 * 96 + off;
        z[c] = q[0] * w00 + q[1] * w01 + q[96] * w10 + q[97] * w11;
    }
    float m = z[0];
    #pragma unroll
    for (int c = 1; c < C; c++) m = fmaxf(m, z[c]);
    float p[C], s = 0.0f;
    #pragma unroll
    for (int c = 0; c < C; c++) { p[c] = expf(z[c] - m); s += p[c]; }
    float inv = 1.0f / s;

    #pragma unroll
    for (int c = 0; c < C; c++) {
        float pc = p[c] * inv;
        int fg = (l == c) ? 1 : 0;
        float err = fabsf((float)fg - pc);
        int bk = (int)(err * (float)NBUCK);
        if (bk > NBUCK - 1) bk = NBUCK - 1;
        if (bk < 0) bk = 0;
        atomicAdd(&cntfg[(size_t)c * NBUCK + bk],
                  0x100000000ull | (unsigned long long)fg);
        atomicAdd(&esum[(size_t)c * NBUCK + bk], err);
    }
}

// Walk buckets descending; one block per class-instance (12 total).
__global__ __launch_bounds__(256) void k_walk(
    const unsigned long long* __restrict__ cntfg, const float* __restrict__ esum,
    double* __restrict__ lov_sum, float* __restrict__ n_present)
{
    const int ITEMS = NBUCK / 256;
    int k = blockIdx.x;                       // 0..11
    int branch = (k < 7) ? 0 : ((k < 10) ? 1 : 2);
    const unsigned long long* cf = cntfg + (size_t)k * NBUCK;
    const float* es = esum + (size_t)k * NBUCK;
    int t = threadIdx.x;

    // per-thread totals over its descending-walk chunk
    unsigned long long tot = 0;
    for (int i = 0; i < ITEMS; i++) {
        int w = t * ITEMS + i;
        int b = NBUCK - 1 - w;
        tot += cf[b];
    }
    __shared__ unsigned long long sc[256];
    sc[t] = tot;
    __syncthreads();
    // inclusive Hillis-Steele scan
    for (int o = 1; o < 256; o <<= 1) {
        unsigned long long add = (t >= o) ? sc[t - o] : 0ull;
        __syncthreads();
        sc[t] += add;
        __syncthreads();
    }
    unsigned long long total = sc[255];
    unsigned long long excl = sc[t] - tot;
    unsigned int G = (unsigned int)(total & 0xffffffffu);
    unsigned int r = (unsigned int)(excl >> 32);
    unsigned int F = (unsigned int)(excl & 0xffffffffu);

    float contrib = 0.0f;
    if (G > 0) {
        float fG = (float)G;
        float j_prev = 1.0f - (fG - (float)F) / fmaxf(fG + (float)r - (float)F, 1.0f);
        for (int i = 0; i < ITEMS; i++) {
            int w = t * ITEMS + i;
            int b = NBUCK - 1 - w;
            unsigned long long cfb = cf[b];
            unsigned int n = (unsigned int)(cfb >> 32);
            unsigned int f = (unsigned int)(cfb & 0xffffffffu);
            if (n) {
                r += n; F += f;
                float j = 1.0f - (fG - (float)F) / fmaxf(fG + (float)r - (float)F, 1.0f);
                contrib += (es[b] / (float)n) * (j - j_prev);
                j_prev = j;
            }
        }
    }

    __shared__ float sf[256];
    sf[t] = contrib;
    __syncthreads();
    for (int o = 128; o > 0; o >>= 1) {
        if (t < o) sf[t] += sf[t + o];
        __syncthreads();
    }
    if (t == 0 && G > 0) {
        atomicAdd(&lov_sum[branch], (double)sf[0]);
        atomicAdd(&n_present[branch], 1.0f);
    }
}

__global__ void k_final(const double* __restrict__ ce_sum, const double* __restrict__ dsn_sum,
                        const double* __restrict__ lov_sum, const float* __restrict__ n_present,
                        const unsigned int* __restrict__ valid_cnt, float* __restrict__ out)
{
    float cnt = fmaxf((float)*valid_cnt, 1.0f);
    float r = (float)(*ce_sum) / cnt
            + (float)lov_sum[0] / fmaxf(n_present[0], 1.0f)
            + 0.4f * ((float)lov_sum[1] / fmaxf(n_present[1], 1.0f))
            + 0.4f * ((float)lov_sum[2] / fmaxf(n_present[2], 1.0f))
            + 0.4f * ((float)(*dsn_sum) / cnt);
    out[0] = r;
}

extern "C" void kernel_launch(void* const* d_in, const int* in_sizes, int n_in,
                              void* d_out, int out_size, void* d_ws, size_t ws_size,
                              hipStream_t stream)
{
    const float* p0 = (const float*)d_in[0];   // [4,7,96,96]
    const float* p1 = (const float*)d_in[1];   // [4,3,96,96]
    const float* p2 = (const float*)d_in[2];   // [4,2,96,96]
    const float* pd = (const float*)d_in[3];   // [4,7,96,96]
    const int* t0 = (const int*)d_in[4];       // [4,384,384]
    const int* t1 = (const int*)d_in[5];
    const int* t2 = (const int*)d_in[6];

    char* ws = (char*)d_ws;
    double* ce_sum = (double*)(ws + 0);
    double* dsn_sum = (double*)(ws + 8);
    double* lov_sum = (double*)(ws + 16);
    float* n_present = (float*)(ws + 40);
    unsigned int* valid_cnt = (unsigned int*)(ws + 52);
    unsigned long long* cntfg = (unsigned long long*)(ws + 64);
    float* esum = (float*)(ws + 64 + 12ull * NBUCK * 8);

    size_t total_ws = 64 + 12ull * NBUCK * 8 + 12ull * NBUCK * 4;
    hipMemsetAsync(d_ws, 0, total_ws, stream);

    int blocks = (PIX + 255) / 256;
    k_branch0<<<blocks, 256, 0, stream>>>(p0, pd, t0, cntfg, esum, ce_sum, dsn_sum, valid_cnt);
    k_lov<3><<<blocks, 256, 0, stream>>>(p1, t1, cntfg + 7ull * NBUCK, esum + 7ull * NBUCK);
    k_lov<2><<<blocks, 256, 0, stream>>>(p2, t2, cntfg + 10ull * NBUCK, esum + 10ull * NBUCK);
    k_walk<<<12, 256, 0, stream>>>(cntfg, esum, lov_sum, n_present);
    k_final<<<1, 1, 0, stream>>>(ce_sum, dsn_sum, lov_sum, n_present, valid_cnt, (float*)d_out);
}

// Round 2
// 144.143 us; speedup vs baseline: 8.1597x; 8.1597x over previous
//
#include <hip/hip_runtime.h>

#define NBUCK 1024
#define NCLS 12              // 7 + 3 + 2 class-instances
#define IGNORE_LBL 255
#define PIX (4*384*384)

// ws layout:
//  0:  double ce_sum
//  8:  double dsn_sum
// 16:  double lov_sum[3]
// 40:  float  n_present[3]
// 52:  uint   valid_cnt
// 64:  u32    slices[nblk][12][NBUCK]   packed (count<<16)|fg  (plain stores, block-private)

__device__ __forceinline__ void bilin_coords(int y, int x, int& y0, int& x0,
                                             float& w00, float& w01, float& w10, float& w11)
{
    const float scale = 95.0f / 383.0f;   // align_corners=True, 96 -> 384
    float sy = y * scale, sx = x * scale;
    y0 = (int)sy; if (y0 > 94) y0 = 94;
    x0 = (int)sx; if (x0 > 94) x0 = 94;
    float ty = sy - (float)y0, tx = sx - (float)x0;
    w00 = (1.0f - ty) * (1.0f - tx);
    w01 = (1.0f - ty) * tx;
    w10 = ty * (1.0f - tx);
    w11 = ty * tx;
}

template<int C>
__device__ __forceinline__ void gather_logits(const float* __restrict__ pr, int base_b, int off,
                                              float w00, float w01, float w10, float w11,
                                              float* z)
{
    #pragma unroll
    for (int c = 0; c < C; c++) {
        const float* q = pr + base_b * C + c * 96 * 96 + off;
        z[c] = q[0] * w00 + q[1] * w01 + q[96] * w10 + q[97] * w11;
    }
}

template<int C>
__device__ __forceinline__ void hist_probs(const float* z, int l, unsigned int* h)
{
    float m = z[0];
    #pragma unroll
    for (int c = 1; c < C; c++) m = fmaxf(m, z[c]);
    float p[C], s = 0.0f;
    #pragma unroll
    for (int c = 0; c < C; c++) { p[c] = __expf(z[c] - m); s += p[c]; }
    float inv = 1.0f / s;
    #pragma unroll
    for (int c = 0; c < C; c++) {
        float pc = p[c] * inv;
        unsigned int fg = (l == c) ? 1u : 0u;
        float err = fabsf((float)fg - pc);
        int bk = (int)(err * (float)NBUCK);
        if (bk > NBUCK - 1) bk = NBUCK - 1;
        if (bk < 0) bk = 0;
        atomicAdd(&h[c * NBUCK + bk], 0x10000u | fg);
    }
}

// Fused: bilinear(96->384) for all 4 pred tensors, CE for pred/pred_dsn,
// LDS bucket-histograms for all 12 lovasz class-instances.
__global__ __launch_bounds__(256) void k_main(
    const float* __restrict__ p0, const float* __restrict__ p1,
    const float* __restrict__ p2, const float* __restrict__ pdsn,
    const int* __restrict__ t0, const int* __restrict__ t1, const int* __restrict__ t2,
    unsigned int* __restrict__ slices,
    double* __restrict__ ce_sum, double* __restrict__ dsn_sum,
    unsigned int* __restrict__ valid_cnt, int nblk)
{
    __shared__ unsigned int h[NCLS * NBUCK];           // 48 KB
    __shared__ float r1[256], r2[256];
    __shared__ int r3[256];

    int t = threadIdx.x;
    for (int i = t; i < NCLS * NBUCK; i += 256) h[i] = 0u;
    __syncthreads();

    int chunk = (PIX + nblk - 1) / nblk;
    int start = blockIdx.x * chunk;
    int end = start + chunk; if (end > PIX) end = PIX;

    float nll_acc = 0.0f, nll2_acc = 0.0f;
    int vcnt = 0;

    for (int idx = start + t; idx < end; idx += 256) {
        int x = idx % 384;
        int y = (idx / 384) % 384;
        int b = idx / (384 * 384);
        int y0, x0; float w00, w01, w10, w11;
        bilin_coords(y, x, y0, x0, w00, w01, w10, w11);
        int off = y0 * 96 + x0;
        int base_b = b * 96 * 96;

        // ---- branch 0: 7 classes, CE + lovasz, plus DSN CE ----
        int l0 = t0[idx];
        if (l0 != IGNORE_LBL) {
            float z[7], z2[7];
            gather_logits<7>(p0, base_b, off, w00, w01, w10, w11, z);
            gather_logits<7>(pdsn, base_b, off, w00, w01, w10, w11, z2);

            int lc = l0; if (lc < 0) lc = 0; if (lc > 6) lc = 6;
            float m = z[0];
            #pragma unroll
            for (int c = 1; c < 7; c++) m = fmaxf(m, z[c]);
            float s = 0.0f;
            #pragma unroll
            for (int c = 0; c < 7; c++) s += __expf(z[c] - m);
            nll_acc += __logf(s) + m - z[lc];

            float m2 = z2[0];
            #pragma unroll
            for (int c = 1; c < 7; c++) m2 = fmaxf(m2, z2[c]);
            float s2 = 0.0f;
            #pragma unroll
            for (int c = 0; c < 7; c++) s2 += __expf(z2[c] - m2);
            nll2_acc += __logf(s2) + m2 - z2[lc];
            vcnt++;

            hist_probs<7>(z, l0, h);
        }

        // ---- branch 1: 3 classes ----
        int l1 = t1[idx];
        if (l1 != IGNORE_LBL) {
            float z[3];
            gather_logits<3>(p1, base_b, off, w00, w01, w10, w11, z);
            hist_probs<3>(z, l1, h + 7 * NBUCK);
        }

        // ---- branch 2: 2 classes ----
        int l2 = t2[idx];
        if (l2 != IGNORE_LBL) {
            float z[2];
            gather_logits<2>(p2, base_b, off, w00, w01, w10, w11, z);
            hist_probs<2>(z, l2, h + 10 * NBUCK);
        }
    }

    // block reduce CE terms
    r1[t] = nll_acc; r2[t] = nll2_acc; r3[t] = vcnt;
    __syncthreads();
    for (int o = 128; o > 0; o >>= 1) {
        if (t < o) { r1[t] += r1[t + o]; r2[t] += r2[t + o]; r3[t] += r3[t + o]; }
        __syncthreads();
    }
    if (t == 0) {
        atomicAdd(ce_sum, (double)r1[0]);
        atomicAdd(dsn_sum, (double)r2[0]);
        atomicAdd(valid_cnt, (unsigned int)r3[0]);
    }

    // flush block-private histogram slice with plain coalesced stores
    unsigned int* dst = slices + (size_t)blockIdx.x * (NCLS * NBUCK);
    for (int i = t; i < NCLS * NBUCK; i += 256) dst[i] = h[i];
}

// One block per class-instance: reduce slices, then descending bucket walk.
__global__ __launch_bounds__(256) void k_walk(
    const unsigned int* __restrict__ slices,
    double* __restrict__ lov_sum, float* __restrict__ n_present, int nslice)
{
    const int ITEMS = NBUCK / 256;                 // 4
    int k = blockIdx.x;                            // 0..11
    int branch = (k < 7) ? 0 : ((k < 10) ? 1 : 2);
    int t = threadIdx.x;

    // reduce slices for this thread's descending buckets
    unsigned long long loc[ITEMS];
    unsigned long long tot = 0;
    #pragma unroll
    for (int i = 0; i < ITEMS; i++) {
        int b = NBUCK - 1 - (t * ITEMS + i);
        unsigned int cnt = 0, fg = 0;
        for (int s = 0; s < nslice; s++) {
            unsigned int v = slices[((size_t)s * NCLS + k) * NBUCK + b];
            cnt += v >> 16;
            fg += v & 0xffffu;
        }
        loc[i] = ((unsigned long long)cnt << 32) | fg;
        tot += loc[i];
    }

    __shared__ unsigned long long sc[256];
    sc[t] = tot;
    __syncthreads();
    for (int o = 1; o < 256; o <<= 1) {
        unsigned long long add = (t >= o) ? sc[t - o] : 0ull;
        __syncthreads();
        sc[t] += add;
        __syncthreads();
    }
    unsigned long long total = sc[255];
    unsigned long long excl = sc[t] - tot;
    unsigned int G = (unsigned int)(total & 0xffffffffu);

    float contrib = 0.0f;
    if (G > 0) {
        unsigned int r = (unsigned int)(excl >> 32);
        unsigned int F = (unsigned int)(excl & 0xffffffffu);
        float fG = (float)G;
        float j_prev = 1.0f - (fG - (float)F) / fmaxf(fG + (float)r - (float)F, 1.0f);
        #pragma unroll
        for (int i = 0; i < ITEMS; i++) {
            int b = NBUCK - 1 - (t * ITEMS + i);
            unsigned int n = (unsigned int)(loc[i] >> 32);
            unsigned int f = (unsigned int)(loc[i] & 0xffffffffu);
            if (n) {
                r += n; F += f;
                float j = 1.0f - (fG - (float)F) / fmaxf(fG + (float)r - (float)F, 1.0f);
                float center = ((float)b + 0.5f) * (1.0f / (float)NBUCK);
                contrib += center * (j - j_prev);
                j_prev = j;
            }
        }
    }

    __shared__ float sf[256];
    sf[t] = contrib;
    __syncthreads();
    for (int o = 128; o > 0; o >>= 1) {
        if (t < o) sf[t] += sf[t + o];
        __syncthreads();
    }
    if (t == 0 && G > 0) {
        atomicAdd(&lov_sum[branch], (double)sf[0]);
        atomicAdd(&n_present[branch], 1.0f);
    }
}

__global__ void k_final(const double* __restrict__ ce_sum, const double* __restrict__ dsn_sum,
                        const double* __restrict__ lov_sum, const float* __restrict__ n_present,
                        const unsigned int* __restrict__ valid_cnt, float* __restrict__ out)
{
    float cnt = fmaxf((float)*valid_cnt, 1.0f);
    float r = (float)(*ce_sum) / cnt
            + (float)lov_sum[0] / fmaxf(n_present[0], 1.0f)
            + 0.4f * ((float)lov_sum[1] / fmaxf(n_present[1], 1.0f))
            + 0.4f * ((float)lov_sum[2] / fmaxf(n_present[2], 1.0f))
            + 0.4f * ((float)(*dsn_sum) / cnt);
    out[0] = r;
}

extern "C" void kernel_launch(void* const* d_in, const int* in_sizes, int n_in,
                              void* d_out, int out_size, void* d_ws, size_t ws_size,
                              hipStream_t stream)
{
    const float* p0 = (const float*)d_in[0];   // [4,7,96,96]
    const float* p1 = (const float*)d_in[1];   // [4,3,96,96]
    const float* p2 = (const float*)d_in[2];   // [4,2,96,96]
    const float* pd = (const float*)d_in[3];   // [4,7,96,96]
    const int* t0 = (const int*)d_in[4];       // [4,384,384]
    const int* t1 = (const int*)d_in[5];
    const int* t2 = (const int*)d_in[6];

    char* ws = (char*)d_ws;
    double* ce_sum = (double*)(ws + 0);
    double* dsn_sum = (double*)(ws + 8);
    double* lov_sum = (double*)(ws + 16);
    float* n_present = (float*)(ws + 40);
    unsigned int* valid_cnt = (unsigned int*)(ws + 52);
    unsigned int* slices = (unsigned int*)(ws + 64);

    // choose block count so block-private slices fit ws_size
    // (floor config 24 blocks = 1,179,712 B total, proven available last round)
    const size_t slice_bytes = (size_t)NCLS * NBUCK * 4;
    int nblk = 24;
    const int cands[5] = {256, 128, 64, 32, 24};
    for (int i = 0; i < 5; i++) {
        if (64 + (size_t)cands[i] * slice_bytes <= ws_size) { nblk = cands[i]; break; }
    }

    hipMemsetAsync(d_ws, 0, 64, stream);   // zero scalar accumulators only

    k_main<<<nblk, 256, 0, stream>>>(p0, p1, p2, pd, t0, t1, t2, slices,
                                     ce_sum, dsn_sum, valid_cnt, nblk);
    k_walk<<<12, 256, 0, stream>>>(slices, lov_sum, n_present, nblk);
    k_final<<<1, 1, 0, stream>>>(ce_sum, dsn_sum, lov_sum, n_present, valid_cnt, (float*)d_out);
}

// Round 3
// 53.769 us; speedup vs baseline: 21.8743x; 2.6808x over previous
//
#include <hip/hip_runtime.h>

#define NBUCK 256
#define NCLS 12              // 7 + 3 + 2 class-instances
#define NCHUNK 16            // merge-tree fan-in chunks
#define IGNORE_LBL 255
#define PIX (4*384*384)

// ws layout:
//  0:   double ce_sum
//  8:   double dsn_sum
// 16:   double lov_sum[3]
// 40:   float  n_present[3]
// 52:   uint   valid_cnt
// 64:   u32    partial[NCHUNK][NCLS][NBUCK]   packed (count<<16)|fg   (196,608 B)
// then: u32    slices[nblk][NCLS][NBUCK]      packed (count<<16)|fg   (12 KB each)

__device__ __forceinline__ void bilin_coords(int y, int x, int& y0, int& x0,
                                             float& w00, float& w01, float& w10, float& w11)
{
    const float scale = 95.0f / 383.0f;   // align_corners=True, 96 -> 384
    float sy = y * scale, sx = x * scale;
    y0 = (int)sy; if (y0 > 94) y0 = 94;
    x0 = (int)sx; if (x0 > 94) x0 = 94;
    float ty = sy - (float)y0, tx = sx - (float)x0;
    w00 = (1.0f - ty) * (1.0f - tx);
    w01 = (1.0f - ty) * tx;
    w10 = ty * (1.0f - tx);
    w11 = ty * tx;
}

template<int C>
__device__ __forceinline__ void gather_logits(const float* __restrict__ pr, int base_b, int off,
                                              float w00, float w01, float w10, float w11,
                                              float* z)
{
    #pragma unroll
    for (int c = 0; c < C; c++) {
        const float* q = pr + base_b * C + c * 96 * 96 + off;
        z[c] = q[0] * w00 + q[1] * w01 + q[96] * w10 + q[97] * w11;
    }
}

template<int C>
__device__ __forceinline__ void hist_probs(const float* z, int l, unsigned int* h)
{
    float m = z[0];
    #pragma unroll
    for (int c = 1; c < C; c++) m = fmaxf(m, z[c]);
    float p[C], s = 0.0f;
    #pragma unroll
    for (int c = 0; c < C; c++) { p[c] = __expf(z[c] - m); s += p[c]; }
    float inv = 1.0f / s;
    #pragma unroll
    for (int c = 0; c < C; c++) {
        float pc = p[c] * inv;
        unsigned int fg = (l == c) ? 1u : 0u;
        float err = fabsf((float)fg - pc);
        int bk = (int)(err * (float)NBUCK);
        if (bk > NBUCK - 1) bk = NBUCK - 1;
        if (bk < 0) bk = 0;
        atomicAdd(&h[c * NBUCK + bk], 0x10000u | fg);
    }
}

// Fused: bilinear(96->384) for all 4 pred tensors, CE for pred/pred_dsn,
// LDS bucket-histograms for all 12 lovasz class-instances.
__global__ __launch_bounds__(256) void k_main(
    const float* __restrict__ p0, const float* __restrict__ p1,
    const float* __restrict__ p2, const float* __restrict__ pdsn,
    const int* __restrict__ t0, const int* __restrict__ t1, const int* __restrict__ t2,
    unsigned int* __restrict__ slices,
    double* __restrict__ ce_sum, double* __restrict__ dsn_sum,
    unsigned int* __restrict__ valid_cnt, int nblk)
{
    __shared__ unsigned int h[NCLS * NBUCK];           // 12 KB
    __shared__ float r1[256], r2[256];
    __shared__ int r3[256];

    int t = threadIdx.x;
    for (int i = t; i < NCLS * NBUCK; i += 256) h[i] = 0u;
    __syncthreads();

    int chunk = (PIX + nblk - 1) / nblk;
    int start = blockIdx.x * chunk;
    int end = start + chunk; if (end > PIX) end = PIX;

    float nll_acc = 0.0f, nll2_acc = 0.0f;
    int vcnt = 0;

    for (int idx = start + t; idx < end; idx += 256) {
        int x = idx % 384;
        int y = (idx / 384) % 384;
        int b = idx / (384 * 384);
        int y0, x0; float w00, w01, w10, w11;
        bilin_coords(y, x, y0, x0, w00, w01, w10, w11);
        int off = y0 * 96 + x0;
        int base_b = b * 96 * 96;

        // ---- branch 0: 7 classes, CE + lovasz, plus DSN CE ----
        int l0 = t0[idx];
        if (l0 != IGNORE_LBL) {
            float z[7], z2[7];
            gather_logits<7>(p0, base_b, off, w00, w01, w10, w11, z);
            gather_logits<7>(pdsn, base_b, off, w00, w01, w10, w11, z2);

            int lc = l0; if (lc < 0) lc = 0; if (lc > 6) lc = 6;
            float m = z[0];
            #pragma unroll
            for (int c = 1; c < 7; c++) m = fmaxf(m, z[c]);
            float s = 0.0f;
            #pragma unroll
            for (int c = 0; c < 7; c++) s += __expf(z[c] - m);
            nll_acc += __logf(s) + m - z[lc];

            float m2 = z2[0];
            #pragma unroll
            for (int c = 1; c < 7; c++) m2 = fmaxf(m2, z2[c]);
            float s2 = 0.0f;
            #pragma unroll
            for (int c = 0; c < 7; c++) s2 += __expf(z2[c] - m2);
            nll2_acc += __logf(s2) + m2 - z2[lc];
            vcnt++;

            hist_probs<7>(z, l0, h);
        }

        // ---- branch 1: 3 classes ----
        int l1 = t1[idx];
        if (l1 != IGNORE_LBL) {
            float z[3];
            gather_logits<3>(p1, base_b, off, w00, w01, w10, w11, z);
            hist_probs<3>(z, l1, h + 7 * NBUCK);
        }

        // ---- branch 2: 2 classes ----
        int l2 = t2[idx];
        if (l2 != IGNORE_LBL) {
            float z[2];
            gather_logits<2>(p2, base_b, off, w00, w01, w10, w11, z);
            hist_probs<2>(z, l2, h + 10 * NBUCK);
        }
    }

    // block reduce CE terms
    r1[t] = nll_acc; r2[t] = nll2_acc; r3[t] = vcnt;
    __syncthreads();
    for (int o = 128; o > 0; o >>= 1) {
        if (t < o) { r1[t] += r1[t + o]; r2[t] += r2[t + o]; r3[t] += r3[t + o]; }
        __syncthreads();
    }
    if (t == 0) {
        atomicAdd(ce_sum, (double)r1[0]);
        atomicAdd(dsn_sum, (double)r2[0]);
        atomicAdd(valid_cnt, (unsigned int)r3[0]);
    }

    // flush block-private histogram slice with plain coalesced stores
    unsigned int* dst = slices + (size_t)blockIdx.x * (NCLS * NBUCK);
    for (int i = t; i < NCLS * NBUCK; i += 256) dst[i] = h[i];
}

// Merge tree stage 1: 12 classes x NCHUNK slice-chunks blocks.
// Each block sums its slice-chunk for one class, plain-stores packed u32.
// Per-chunk counts <= PIX/NCHUNK = 36864 < 2^16, so packing stays safe.
__global__ __launch_bounds__(256) void k_merge(
    const unsigned int* __restrict__ slices, unsigned int* __restrict__ partial,
    int nblk)
{
    int k = blockIdx.x % NCLS;
    int cy = blockIdx.x / NCLS;
    int b = threadIdx.x;                       // bucket (NBUCK == blockDim)
    int s0 = (cy * nblk) / NCHUNK;
    int s1 = ((cy + 1) * nblk) / NCHUNK;

    unsigned int acc = 0;
    for (int s = s0; s < s1; s++)
        acc += slices[((size_t)s * NCLS + k) * NBUCK + b];

    partial[((size_t)cy * NCLS + k) * NBUCK + b] = acc;
}

// One block per class-instance: final bucket reduce + descending walk.
__global__ __launch_bounds__(256) void k_walk(
    const unsigned int* __restrict__ partial,
    double* __restrict__ lov_sum, float* __restrict__ n_present)
{
    int k = blockIdx.x;                            // 0..11
    int branch = (k < 7) ? 0 : ((k < 10) ? 1 : 2);
    int t = threadIdx.x;
    int b = NBUCK - 1 - t;                         // descending: thread t owns bucket b

    unsigned int cnt = 0, fg = 0;
    #pragma unroll
    for (int cy = 0; cy < NCHUNK; cy++) {
        unsigned int v = partial[((size_t)cy * NCLS + k) * NBUCK + b];
        cnt += v >> 16;
        fg += v & 0xffffu;
    }
    unsigned long long own = ((unsigned long long)cnt << 32) | fg;

    __shared__ unsigned long long sc[256];
    sc[t] = own;
    __syncthreads();
    for (int o = 1; o < 256; o <<= 1) {
        unsigned long long add = (t >= o) ? sc[t - o] : 0ull;
        __syncthreads();
        sc[t] += add;
        __syncthreads();
    }
    unsigned long long total = sc[255];
    unsigned long long excl = sc[t] - own;
    unsigned int G = (unsigned int)(total & 0xffffffffu);

    float contrib = 0.0f;
    if (G > 0 && cnt > 0) {
        unsigned int r = (unsigned int)(excl >> 32);
        unsigned int F = (unsigned int)(excl & 0xffffffffu);
        float fG = (float)G;
        float j_prev = 1.0f - (fG - (float)F) / fmaxf(fG + (float)r - (float)F, 1.0f);
        r += cnt; F += fg;
        float j = 1.0f - (fG - (float)F) / fmaxf(fG + (float)r - (float)F, 1.0f);
        float center = ((float)b + 0.5f) * (1.0f / (float)NBUCK);
        contrib = center * (j - j_prev);
    }

    __shared__ float sf[256];
    sf[t] = contrib;
    __syncthreads();
    for (int o = 128; o > 0; o >>= 1) {
        if (t < o) sf[t] += sf[t + o];
        __syncthreads();
    }
    if (t == 0 && G > 0) {
        atomicAdd(&lov_sum[branch], (double)sf[0]);
        atomicAdd(&n_present[branch], 1.0f);
    }
}

__global__ void k_final(const double* __restrict__ ce_sum, const double* __restrict__ dsn_sum,
                        const double* __restrict__ lov_sum, const float* __restrict__ n_present,
                        const unsigned int* __restrict__ valid_cnt, float* __restrict__ out)
{
    float cnt = fmaxf((float)*valid_cnt, 1.0f);
    float r = (float)(*ce_sum) / cnt
            + (float)lov_sum[0] / fmaxf(n_present[0], 1.0f)
            + 0.4f * ((float)lov_sum[1] / fmaxf(n_present[1], 1.0f))
            + 0.4f * ((float)lov_sum[2] / fmaxf(n_present[2], 1.0f))
            + 0.4f * ((float)(*dsn_sum) / cnt);
    out[0] = r;
}

extern "C" void kernel_launch(void* const* d_in, const int* in_sizes, int n_in,
                              void* d_out, int out_size, void* d_ws, size_t ws_size,
                              hipStream_t stream)
{
    const float* p0 = (const float*)d_in[0];   // [4,7,96,96]
    const float* p1 = (const float*)d_in[1];   // [4,3,96,96]
    const float* p2 = (const float*)d_in[2];   // [4,2,96,96]
    const float* pd = (const float*)d_in[3];   // [4,7,96,96]
    const int* t0 = (const int*)d_in[4];       // [4,384,384]
    const int* t1 = (const int*)d_in[5];
    const int* t2 = (const int*)d_in[6];

    char* ws = (char*)d_ws;
    double* ce_sum = (double*)(ws + 0);
    double* dsn_sum = (double*)(ws + 8);
    double* lov_sum = (double*)(ws + 16);
    float* n_present = (float*)(ws + 40);
    unsigned int* valid_cnt = (unsigned int*)(ws + 52);
    const size_t partial_bytes = (size_t)NCHUNK * NCLS * NBUCK * 4;   // 196,608
    unsigned int* partial = (unsigned int*)(ws + 64);
    unsigned int* slices = (unsigned int*)(ws + 64 + partial_bytes);

    // choose main-block count: as many as fit workspace, cap 512, multiple of NCHUNK
    const size_t slice_bytes = (size_t)NCLS * NBUCK * 4;              // 12,288
    long long avail = (long long)ws_size - 64 - (long long)partial_bytes;
    int nblk = (int)(avail / (long long)slice_bytes);
    if (nblk > 512) nblk = 512;
    nblk -= nblk % NCHUNK;
    if (nblk < NCHUNK) nblk = NCHUNK;

    hipMemsetAsync(d_ws, 0, 64, stream);   // zero scalar accumulators only

    k_main<<<nblk, 256, 0, stream>>>(p0, p1, p2, pd, t0, t1, t2, slices,
                                     ce_sum, dsn_sum, valid_cnt, nblk);
    k_merge<<<NCLS * NCHUNK, NBUCK, 0, stream>>>(slices, partial, nblk);
    k_walk<<<NCLS, NBUCK, 0, stream>>>(partial, lov_sum, n_present);
    k_final<<<1, 1, 0, stream>>>(ce_sum, dsn_sum, lov_sum, n_present, valid_cnt, (float*)d_out);
}

// Round 4
// 39.167 us; speedup vs baseline: 30.0294x; 1.3728x over previous
//
#include <hip/hip_runtime.h>

#define NBUCK 128
#define NCLS 12              // 7 + 3 + 2 class-instances
#define NCHUNK 16
#define NBMAIN 576           // (4*384*384/4 groups) / 256 threads = 576 blocks, 1 group/thread
#define SLICES_PER_CHUNK (NBMAIN / NCHUNK)   // 36
#define IGNORE_LBL 255
#define PIX (4*384*384)

// unaligned-capable float4 (global dwordx4 needs only 4B alignment on CDNA)
typedef float float4a __attribute__((ext_vector_type(4), aligned(4)));

// ws layout:
//  0:       u32    partial[NCHUNK][NCLS][NBUCK]   98,304 B
//  98304:   float4 ce_part[NBMAIN]                 9,216 B
//  107520:  u32    slices[NBMAIN][NCLS][NBUCK] 3,538,944 B
// total 3,646,464 B  (< 6.29 MB proven available)

__global__ __launch_bounds__(256) void k_main(
    const float* __restrict__ p0, const float* __restrict__ p1,
    const float* __restrict__ p2, const float* __restrict__ pdsn,
    const int* __restrict__ t0, const int* __restrict__ t1, const int* __restrict__ t2,
    unsigned int* __restrict__ slices, float4* __restrict__ ce_part)
{
    __shared__ unsigned int h[NCLS * NBUCK];     // 6 KB
    __shared__ float cw[4][3];
    int t = threadIdx.x;
    #pragma unroll
    for (int i = t; i < NCLS * NBUCK; i += 256) h[i] = 0u;
    __syncthreads();

    int g = blockIdx.x * 256 + t;                // group id, exactly PIX/4 groups
    int gx = g % 96;                             // group column (4 output px each)
    int row = g / 96;                            // 0..1535
    int y = row % 384;
    int b = row / 384;
    int x4 = gx * 4;

    const float scale = 95.0f / 383.0f;          // align_corners=True, 96 -> 384
    float sy = y * scale;
    int y0 = (int)sy; if (y0 > 94) y0 = 94;
    float ty = sy - (float)y0;
    float oty = 1.0f - ty;

    float sx0 = (float)x4 * scale;
    int X0 = (int)sx0; if (X0 > 92) X0 = 92;     // cols X0..X0+3 cover all 4 px needs

    // horizontal tent weights (exact bilinear), pre-scaled by vertical weights
    float Wa[4][4], Wb[4][4];
    #pragma unroll
    for (int i = 0; i < 4; i++) {
        float sx = (float)(x4 + i) * scale;
        #pragma unroll
        for (int j = 0; j < 4; j++) {
            float w = fmaxf(1.0f - fabsf(sx - (float)(X0 + j)), 0.0f);
            Wa[i][j] = w * oty;
            Wb[i][j] = w * ty;
        }
    }

    const int rb = y0 * 96 + X0;
    const float* A0 = p0   + b * 7 * 9216 + rb;
    const float* Ad = pdsn + b * 7 * 9216 + rb;
    const float* A1 = p1   + b * 3 * 9216 + rb;
    const float* A2 = p2   + b * 2 * 9216 + rb;

    int4 L0 = *(const int4*)(t0 + g * 4);
    int4 L1 = *(const int4*)(t1 + g * 4);
    int4 L2 = *(const int4*)(t2 + g * 4);
    int l0v[4] = {L0.x, L0.y, L0.z, L0.w};
    int l1v[4] = {L1.x, L1.y, L1.z, L1.w};
    int l2v[4] = {L2.x, L2.y, L2.z, L2.w};

    auto interp4 = [&](const float* A, int c, float zout[4]) {
        float4a r0 = *(const float4a*)(A + c * 9216);
        float4a r1 = *(const float4a*)(A + c * 9216 + 96);
        #pragma unroll
        for (int i = 0; i < 4; i++) {
            zout[i] = r0.x*Wa[i][0] + r0.y*Wa[i][1] + r0.z*Wa[i][2] + r0.w*Wa[i][3]
                    + r1.x*Wb[i][0] + r1.y*Wb[i][1] + r1.z*Wb[i][2] + r1.w*Wb[i][3];
        }
    };
    auto histadd = [&](int cls, int fg, float err) {
        int bk = (int)(err * (float)NBUCK);
        if (bk > NBUCK - 1) bk = NBUCK - 1;
        atomicAdd(&h[cls * NBUCK + bk], 0x10000u | (unsigned)fg);
    };

    float nll = 0.f, nll2 = 0.f; int vc = 0;

    // ---- branch 0: 7 classes (CE + lovasz) ----
    float z0[7][4];
    #pragma unroll
    for (int c = 0; c < 7; c++) interp4(A0, c, z0[c]);

    #pragma unroll
    for (int i = 0; i < 4; i++) {
        int l = l0v[i];
        bool valid = (l != IGNORE_LBL);
        float m = z0[0][i];
        #pragma unroll
        for (int c = 1; c < 7; c++) m = fmaxf(m, z0[c][i]);
        float e[7], s = 0.f;
        #pragma unroll
        for (int c = 0; c < 7; c++) { e[c] = __expf(z0[c][i] - m); s += e[c]; }
        float inv = 1.0f / s;
        float zl = z0[0][i];
        #pragma unroll
        for (int c = 1; c < 7; c++) zl = (l == c) ? z0[c][i] : zl;
        if (valid) {
            nll += __logf(s) + m - zl;
            vc++;
            #pragma unroll
            for (int c = 0; c < 7; c++) {
                int fg = (l == c);
                histadd(c, fg, fabsf((float)fg - e[c] * inv));
            }
        }
    }

    // ---- DSN: 7 classes, CE only, online logsumexp (no z-array) ----
    {
        float m2[4] = {-1e30f, -1e30f, -1e30f, -1e30f};
        float s2[4] = {0.f, 0.f, 0.f, 0.f};
        float zl2[4] = {0.f, 0.f, 0.f, 0.f};
        #pragma unroll
        for (int c = 0; c < 7; c++) {
            float zc[4];
            interp4(Ad, c, zc);
            #pragma unroll
            for (int i = 0; i < 4; i++) {
                float nm = fmaxf(m2[i], zc[i]);
                s2[i] = s2[i] * __expf(m2[i] - nm) + __expf(zc[i] - nm);
                m2[i] = nm;
                zl2[i] = (l0v[i] == c) ? zc[i] : zl2[i];
            }
        }
        #pragma unroll
        for (int i = 0; i < 4; i++)
            if (l0v[i] != IGNORE_LBL) nll2 += __logf(s2[i]) + m2[i] - zl2[i];
    }

    // ---- branch 1: 3 classes ----
    {
        float z1[3][4];
        #pragma unroll
        for (int c = 0; c < 3; c++) interp4(A1, c, z1[c]);
        #pragma unroll
        for (int i = 0; i < 4; i++) {
            int l = l1v[i];
            if (l != IGNORE_LBL) {
                float m = fmaxf(fmaxf(z1[0][i], z1[1][i]), z1[2][i]);
                float e0 = __expf(z1[0][i] - m), e1 = __expf(z1[1][i] - m), e2 = __expf(z1[2][i] - m);
                float inv = 1.0f / (e0 + e1 + e2);
                histadd(7 + 0, (l == 0), fabsf((float)(l == 0) - e0 * inv));
                histadd(7 + 1, (l == 1), fabsf((float)(l == 1) - e1 * inv));
                histadd(7 + 2, (l == 2), fabsf((float)(l == 2) - e2 * inv));
            }
        }
    }

    // ---- branch 2: 2 classes ----
    {
        float z2a[2][4];
        #pragma unroll
        for (int c = 0; c < 2; c++) interp4(A2, c, z2a[c]);
        #pragma unroll
        for (int i = 0; i < 4; i++) {
            int l = l2v[i];
            if (l != IGNORE_LBL) {
                float m = fmaxf(z2a[0][i], z2a[1][i]);
                float e0 = __expf(z2a[0][i] - m), e1 = __expf(z2a[1][i] - m);
                float inv = 1.0f / (e0 + e1);
                histadd(10 + 0, (l == 0), fabsf((float)(l == 0) - e0 * inv));
                histadd(10 + 1, (l == 1), fabsf((float)(l == 1) - e1 * inv));
            }
        }
    }

    // ---- CE block reduce (shfl + tiny LDS), plain store per block ----
    #pragma unroll
    for (int o = 32; o > 0; o >>= 1) {
        nll  += __shfl_down(nll, o);
        nll2 += __shfl_down(nll2, o);
        vc   += __shfl_down(vc, o);
    }
    int wv = t >> 6, ln = t & 63;
    if (ln == 0) { cw[wv][0] = nll; cw[wv][1] = nll2; cw[wv][2] = (float)vc; }
    __syncthreads();                                  // also fences all LDS atomics
    if (t == 0) {
        float a  = cw[0][0] + cw[1][0] + cw[2][0] + cw[3][0];
        float bb = cw[0][1] + cw[1][1] + cw[2][1] + cw[3][1];
        float cc = cw[0][2] + cw[1][2] + cw[2][2] + cw[3][2];
        ce_part[blockIdx.x] = make_float4(a, bb, cc, 0.f);
    }

    // ---- flush block-private histogram (plain coalesced stores) ----
    unsigned int* dst = slices + (size_t)blockIdx.x * (NCLS * NBUCK);
    #pragma unroll
    for (int i = t; i < NCLS * NBUCK; i += 256) dst[i] = h[i];
}

// parallel fan-in: 12 classes x 16 chunks, each block sums 36 slices.
// per-chunk per-bucket count <= 36*1024 = 36,864 < 2^16 -> u16 packing safe.
__global__ __launch_bounds__(128) void k_merge(
    const unsigned int* __restrict__ slices, unsigned int* __restrict__ partial)
{
    int kk = blockIdx.x % NCLS;
    int cy = blockIdx.x / NCLS;
    int bk = threadIdx.x;
    int s0 = cy * SLICES_PER_CHUNK;
    unsigned int acc = 0;
    for (int s = 0; s < SLICES_PER_CHUNK; s++)
        acc += slices[(size_t)((s0 + s) * NCLS + kk) * NBUCK + bk];
    partial[(size_t)(cy * NCLS + kk) * NBUCK + bk] = acc;
}

// single block: CE totals + 3 rounds x 4-class segmented scan-walk + final combine.
// no global atomics, no pre-zeroed memory needed anywhere.
__global__ __launch_bounds__(512) void k_fin(
    const unsigned int* __restrict__ partial, const float4* __restrict__ ce_part,
    float* __restrict__ out)
{
    int t = threadIdx.x;
    __shared__ float ce_tot[3];
    __shared__ float cwf[8][3];
    __shared__ unsigned long long sc[512];
    __shared__ float sf[512];
    __shared__ float cls_lov[NCLS];
    __shared__ float cls_pres[NCLS];

    // Phase A: CE totals from per-block partials
    float a = 0.f, bb = 0.f, cc = 0.f;
    for (int e = t; e < NBMAIN; e += 512) {
        float4 v = ce_part[e];
        a += v.x; bb += v.y; cc += v.z;
    }
    #pragma unroll
    for (int o = 32; o > 0; o >>= 1) {
        a += __shfl_down(a, o); bb += __shfl_down(bb, o); cc += __shfl_down(cc, o);
    }
    if ((t & 63) == 0) { cwf[t >> 6][0] = a; cwf[t >> 6][1] = bb; cwf[t >> 6][2] = cc; }
    __syncthreads();
    if (t == 0) {
        float x = 0.f, y = 0.f, z = 0.f;
        for (int w = 0; w < 8; w++) { x += cwf[w][0]; y += cwf[w][1]; z += cwf[w][2]; }
        ce_tot[0] = x; ce_tot[1] = y; ce_tot[2] = z;
    }

    // Phase B: lovasz walk, 4 classes per round (segmented 128-thread scans)
    int sub = t >> 7;                 // segment 0..3
    int p   = t & 127;                // position in segment
    int bk  = NBUCK - 1 - p;          // descending bucket

    for (int r = 0; r < 3; r++) {
        int kk = r * 4 + sub;
        unsigned int cnt = 0, fg = 0;
        #pragma unroll
        for (int cy = 0; cy < NCHUNK; cy++) {
            unsigned int v = partial[(size_t)(cy * NCLS + kk) * NBUCK + bk];
            cnt += v >> 16; fg += v & 0xffffu;
        }
        unsigned long long own = ((unsigned long long)cnt << 32) | fg;
        __syncthreads();
        sc[t] = own;
        __syncthreads();
        #pragma unroll
        for (int o = 1; o < 128; o <<= 1) {
            unsigned long long add = (p >= o) ? sc[t - o] : 0ull;
            __syncthreads();
            sc[t] += add;
            __syncthreads();
        }
        unsigned long long total = sc[(sub << 7) + 127];
        unsigned long long excl = sc[t] - own;
        unsigned int G = (unsigned int)(total & 0xffffffffu);

        float contrib = 0.f;
        if (G > 0 && cnt > 0) {
            unsigned int rr = (unsigned int)(excl >> 32);
            unsigned int F  = (unsigned int)(excl & 0xffffffffu);
            float fG = (float)G;
            float j0 = 1.0f - (fG - (float)F) / fmaxf(fG + (float)rr - (float)F, 1.0f);
            rr += cnt; F += fg;
            float j1 = 1.0f - (fG - (float)F) / fmaxf(fG + (float)rr - (float)F, 1.0f);
            contrib = (((float)bk + 0.5f) * (1.0f / (float)NBUCK)) * (j1 - j0);
        }
        sf[t] = contrib;
        __syncthreads();
        #pragma unroll
        for (int o = 64; o > 0; o >>= 1) {
            if (p < o) sf[t] += sf[t + o];
            __syncthreads();
        }
        if (p == 0) {
            cls_lov[kk]  = (G > 0) ? sf[t] : 0.f;
            cls_pres[kk] = (G > 0) ? 1.f : 0.f;
        }
    }
    __syncthreads();

    if (t == 0) {
        float l0 = 0.f, p0c = 0.f, l1 = 0.f, p1c = 0.f, l2 = 0.f, p2c = 0.f;
        for (int k = 0; k < 7;  k++) { l0 += cls_lov[k]; p0c += cls_pres[k]; }
        for (int k = 7; k < 10; k++) { l1 += cls_lov[k]; p1c += cls_pres[k]; }
        for (int k = 10; k < 12; k++) { l2 += cls_lov[k]; p2c += cls_pres[k]; }
        float vcnt = fmaxf(ce_tot[2], 1.0f);
        out[0] = ce_tot[0] / vcnt
               + l0 / fmaxf(p0c, 1.f)
               + 0.4f * (l1 / fmaxf(p1c, 1.f))
               + 0.4f * (l2 / fmaxf(p2c, 1.f))
               + 0.4f * (ce_tot[1] / vcnt);
    }
}

extern "C" void kernel_launch(void* const* d_in, const int* in_sizes, int n_in,
                              void* d_out, int out_size, void* d_ws, size_t ws_size,
                              hipStream_t stream)
{
    const float* p0 = (const float*)d_in[0];   // [4,7,96,96]
    const float* p1 = (const float*)d_in[1];   // [4,3,96,96]
    const float* p2 = (const float*)d_in[2];   // [4,2,96,96]
    const float* pd = (const float*)d_in[3];   // [4,7,96,96]
    const int* t0 = (const int*)d_in[4];       // [4,384,384]
    const int* t1 = (const int*)d_in[5];
    const int* t2 = (const int*)d_in[6];

    char* ws = (char*)d_ws;
    unsigned int* partial = (unsigned int*)ws;                    // 98,304 B
    float4* ce_part = (float4*)(ws + 98304);                      // 9,216 B
    unsigned int* slices = (unsigned int*)(ws + 98304 + 9216);    // 3,538,944 B

    k_main<<<NBMAIN, 256, 0, stream>>>(p0, p1, p2, pd, t0, t1, t2, slices, ce_part);
    k_merge<<<NCLS * NCHUNK, 128, 0, stream>>>(slices, partial);
    k_fin<<<1, 512, 0, stream>>>(partial, ce_part, (float*)d_out);
}